// Round 11
// baseline (389.599 us; speedup 1.0000x reference)
//
#include <hip/hip_runtime.h>
#include <hip/hip_bf16.h>
#include <cstdint>
#include <cstddef>

typedef __bf16 bf16;
typedef bf16 bf16x8 __attribute__((ext_vector_type(8)));
typedef bf16 bf16x4 __attribute__((ext_vector_type(4)));
typedef float f32x4 __attribute__((ext_vector_type(4)));
typedef unsigned int u32;

#define DEV static __device__ __forceinline__

DEV f32x4 mfma16(bf16x8 a, bf16x8 b, f32x4 c) {
    return __builtin_amdgcn_mfma_f32_16x16x32_bf16(a, b, c, 0, 0, 0);
}

DEV f32x4 shflx4(f32x4 v, int m) {
    f32x4 r;
    for (int i = 0; i < 4; ++i) r[i] = __shfl_xor(v[i], m, 64);
    return r;
}

DEV bf16x8 cvt8(const float* p) {
    float4 f0 = *(const float4*)p;
    float4 f1 = *(const float4*)(p + 4);
    bf16x8 v;
    v[0] = (bf16)f0.x; v[1] = (bf16)f0.y; v[2] = (bf16)f0.z; v[3] = (bf16)f0.w;
    v[4] = (bf16)f1.x; v[5] = (bf16)f1.y; v[6] = (bf16)f1.z; v[7] = (bf16)f1.w;
    return v;
}

// async global->LDS, 16B/lane; global addr per-lane, LDS base wave-uniform.
DEV void glo(const bf16* g, bf16* l) {
    __builtin_amdgcn_global_load_lds(
        (const __attribute__((address_space(1))) u32*)g,
        (__attribute__((address_space(3))) u32*)l,
        16, 0, 0);
}
DEV void glof(const float* g, float* l) {
    __builtin_amdgcn_global_load_lds(
        (const __attribute__((address_space(1))) u32*)g,
        (__attribute__((address_space(3))) u32*)l,
        16, 0, 0);
}

// XOR-swizzle convention (bf16, 64-col rows): LDS[row][seg] = G[row][seg^(row&7)]
// (seg = 8-elem/16B chunk). Fragment k-seg s of row r lives at seg s^(r&7).
// fp32 64-col rows: seg = 8 floats (32B), same XOR on (row&7).

// ---------------------------------------------------------------------------
// Prep: weight transpose+cvt W[K][N]fp32 -> Wt[N][K]bf16, z<6.
// ---------------------------------------------------------------------------
struct PrepArgs {
    const float* w[6];
    bf16* wt;
};

__global__ __launch_bounds__(256) void prep_kernel(PrepArgs p)
{
    const int z = blockIdx.z;
    const int t = threadIdx.x;
    __shared__ bf16 tile[64][72];
    const float* src = p.w[z];
    bf16* out = p.wt + (size_t)z * 1024 * 1024;
    const int r = t >> 3, c8 = (t & 7) * 8;
    const int row0 = blockIdx.y * 64, col0 = blockIdx.x * 64;
    *(bf16x8*)&tile[r][c8]      = cvt8(&src[(size_t)(row0 + r) * 1024 + col0 + c8]);
    *(bf16x8*)&tile[r + 32][c8] = cvt8(&src[(size_t)(row0 + r + 32) * 1024 + col0 + c8]);
    __syncthreads();
    for (int half = 0; half < 2; ++half) {
        int rr = r + half * 32;
        bf16x8 v;
        for (int j = 0; j < 8; ++j) v[j] = tile[c8 + j][rr];
        *(bf16x8*)&out[(size_t)(col0 + rr) * 1024 + row0 + c8] = v;
    }
}

// ---------------------------------------------------------------------------
// maskprep: mask[b][i][j] fp32 -> maskR[(b,it,jt)][tid][e] bf16, e=(si*4+jc)*4+r
// grid (16 jt, 8 it, 4 b), 256 threads.
// ---------------------------------------------------------------------------
__global__ __launch_bounds__(256) void maskprep_kernel(
    const float* __restrict__ mask, bf16* __restrict__ maskR)
{
    const int jt = blockIdx.x, it = blockIdx.y, b = blockIdx.z;
    __shared__ bf16 Mt[128 * 72];
    const int t = threadIdx.x, lane = t & 63, w = t >> 6;
    const int ln = lane & 15, qd = lane >> 4;
    {
        const int il = t >> 1, jh = (t & 1) * 32;
        const float* src = &mask[((size_t)b * 1024 + it * 128 + il) * 1024 + jt * 64 + jh];
        *(bf16x8*)&Mt[il * 72 + jh]      = cvt8(src);
        *(bf16x8*)&Mt[il * 72 + jh + 8]  = cvt8(src + 8);
        *(bf16x8*)&Mt[il * 72 + jh + 16] = cvt8(src + 16);
        *(bf16x8*)&Mt[il * 72 + jh + 24] = cvt8(src + 24);
    }
    __syncthreads();
    bf16 m[32];
    for (int si = 0; si < 2; ++si)
        for (int jc = 0; jc < 4; ++jc)
            for (int r = 0; r < 4; ++r) {
                const int il = w * 32 + si * 16 + qd * 4 + r;
                const int jl = jc * 16 + ln;
                m[(si * 4 + jc) * 4 + r] = Mt[il * 72 + jl];
            }
    bf16* dst = &maskR[((((size_t)b * 8 + it) * 16 + jt) * 256 + t) * 32];
    for (int c = 0; c < 4; ++c)
        *(bf16x8*)&dst[c * 8] = *(const bf16x8*)&m[c * 8];
}

// ---------------------------------------------------------------------------
// Projection GEMMs, 5 z-slices, A = fp32 input staged via glo (swizzled fp32
// segs), converted to bf16 at fragment read; W bf16 glo+swizzle.
// Grid (32 my, 8 nx, 5): same-A blocks share an XCD (linear%8 = my%8).
// 128x128 tile, 4 waves x 64x64, BK=64.
// Staging units/iter: B = 16 units (4/wave), A = 32 units (8/wave).
// ---------------------------------------------------------------------------
struct ProjArgs {
    const float* A[5];
    const bf16*  W[5];
    const float* bias[5];
    bf16* out[5];
    int vst[5];
};

__global__ __launch_bounds__(256) void proj_gemm(ProjArgs pa)
{
    const int z = blockIdx.z;
    const float* A = pa.A[z];
    const bf16*  W = pa.W[z];
    const int m0 = blockIdx.x * 128, n0 = blockIdx.y * 128;
    __shared__ float Asf[128 * 64];   // 32 KB, swizzled fp32
    __shared__ bf16  Bs[128 * 64];    // 16 KB, swizzled bf16
    const int t = threadIdx.x, lane = t & 63, w = t >> 6;
    const int ln = lane & 15, qd = lane >> 4;
    const int wm0 = (w >> 1) * 64, wn0 = (w & 1) * 64;
    const int lx = ln & 7;
    // B staging coords (bf16): 8 rows/unit, 8 segs of 8 elems
    const int brr = lane >> 3;
    const int bcbs = ((lane & 7) ^ brr) * 8;
    // A staging coords (fp32): 4 rows/unit, lane covers 16B = 4 floats
    const int arr = lane >> 4;             // row in unit 0..3
    const int c16 = lane & 15;
    const int aseg = c16 >> 1, ahalf = c16 & 1;
    f32x4 acc[4][4];
    for (int i = 0; i < 4; ++i)
        for (int j = 0; j < 4; ++j)
            acc[i][j] = (f32x4){0.f, 0.f, 0.f, 0.f};
    for (int ks = 0; ks < 16; ++ks) {
        const int bk = ks * 64;
        __syncthreads();
        // B: 16 units, 4/wave (covers all 128 rows)
        for (int j = 0; j < 4; ++j) {
            const int u = w * 4 + j;
            glo(&W[(size_t)(n0 + u * 8 + brr) * 1024 + bk + bcbs], &Bs[u * 512]);
        }
        // A: 32 units, 8/wave (fp32, covers all 128 rows)
        for (int i = 0; i < 8; ++i) {
            const int u = w * 8 + i;
            const int row = u * 4 + arr;
            const int colf = ((aseg ^ (row & 7)) * 8) + ahalf * 4;
            glof(&A[(size_t)(m0 + row) * 1024 + bk + colf], &Asf[u * 256]);
        }
        __syncthreads();
        for (int kc = 0; kc < 2; ++kc) {
            const int ksg = kc * 4 + qd;
            const int sg = (ksg ^ lx);
            bf16x8 af[4], bfr[4];
            for (int mi = 0; mi < 4; ++mi)
                af[mi] = cvt8(&Asf[(wm0 + mi * 16 + ln) * 64 + sg * 8]);
            for (int ni = 0; ni < 4; ++ni)
                bfr[ni] = *(const bf16x8*)&Bs[(wn0 + ni * 16 + ln) * 64 + sg * 8];
            for (int mi = 0; mi < 4; ++mi)
                for (int ni = 0; ni < 4; ++ni)
                    acc[mi][ni] = mfma16(af[mi], bfr[ni], acc[mi][ni]);
        }
    }
    const float* bias = pa.bias[z];
    bf16* out = pa.out[z];
    const int vst = pa.vst[z];
    for (int ni = 0; ni < 4; ++ni) {
        const int n = n0 + wn0 + ni * 16 + ln;
        const float bv = bias[n];
        for (int mi = 0; mi < 4; ++mi) {
            const int mbase = m0 + wm0 + mi * 16 + qd * 4;
            f32x4 v = acc[mi][ni];
            if (vst) {
                const int b = mbase >> 10, s = mbase & 1023;
                bf16x4 pk;
                for (int r = 0; r < 4; ++r) pk[r] = (bf16)(v[r] + bv);
                *(bf16x4*)&out[((size_t)(b * 1024 + n)) * 1024 + s] = pk;
            } else {
                for (int r = 0; r < 4; ++r)
                    out[(size_t)(mbase + r) * 1024 + n] = (bf16)(v[r] + bv);
            }
        }
    }
}

// ---------------------------------------------------------------------------
// Attention (attn6, round-9 verified): i-tile 128, j-tile 64,
// grid (16h,8it,4b)=512; K/QJ glo+swizzle; V=Va+Vb into pad-68 Vs; mask from
// maskR registers; Ps pad-68, b64 PV reads.
// ---------------------------------------------------------------------------
__global__ __launch_bounds__(256) void attn6_kernel(
    const bf16* __restrict__ Qb, const bf16* __restrict__ Kb, const bf16* __restrict__ TKb,
    const bf16* __restrict__ Va, const bf16* __restrict__ Vb,
    const bf16* __restrict__ maskR, bf16* __restrict__ ctx)
{
    const int h = blockIdx.x, it = blockIdx.y, b = blockIdx.z;
    const int i0 = it * 128;
    __shared__ bf16 Ks[64 * 64];
    __shared__ bf16 QJs[64 * 64];
    __shared__ bf16 Vs[64 * 68];
    __shared__ bf16 Ps[128][68];
    const int t = threadIdx.x, lane = t & 63, w = t >> 6;
    const int ln = lane & 15, qd = lane >> 4;
    const int lx = ln & 7;
    const size_t baseQ = ((size_t)b * 1024) * 1024 + (size_t)h * 64;

    bf16x8 qf[2][2], tkf[2][2];
    for (int si = 0; si < 2; ++si) {
        const size_t row = (size_t)(i0 + w * 32 + si * 16 + ln);
        for (int kc = 0; kc < 2; ++kc) {
            qf[si][kc]  = *(const bf16x8*)&Qb [baseQ + row * 1024 + kc * 32 + qd * 8];
            tkf[si][kc] = *(const bf16x8*)&TKb[baseQ + row * 1024 + kc * 32 + qd * 8];
        }
    }

    f32x4 O[2][4];
    f32x4 psum[2];
    for (int si = 0; si < 2; ++si) {
        psum[si] = (f32x4){0.f, 0.f, 0.f, 0.f};
        for (int dc = 0; dc < 4; ++dc) O[si][dc] = (f32x4){0.f, 0.f, 0.f, 0.f};
    }

    const float c1 = 0.045084439f;   // log2(e)/32
    const float c2 = 1.442695041f;   // log2(e)

    const size_t mtile0 = (((size_t)b * 8 + it) * 16) * 256 + t;

    for (int jt = 0; jt < 16; ++jt) {
        const int j0 = jt * 64;
        __syncthreads();
        {
            const int rr = lane >> 3;
            const int cbs = ((lane & 7) ^ rr) * 8;
            for (int i = 0; i < 4; ++i) {
                const int u = w * 4 + i;
                if (u < 8) {
                    glo(&Kb[baseQ + (size_t)(j0 + u * 8 + rr) * 1024 + cbs], &Ks[u * 512]);
                } else {
                    const int s = u - 8;
                    glo(&Qb[baseQ + (size_t)(j0 + s * 8 + rr) * 1024 + cbs], &QJs[s * 512]);
                }
            }
        }
        {
            const int vrow = t >> 2, vcol = (t & 3) * 16;
            const size_t va = ((size_t)b * 1024 + h * 64 + vrow) * 1024 + j0 + vcol;
            bf16x8 a0 = *(const bf16x8*)&Va[va];
            bf16x8 a1 = *(const bf16x8*)&Va[va + 8];
            bf16x8 b0 = *(const bf16x8*)&Vb[va];
            bf16x8 b1 = *(const bf16x8*)&Vb[va + 8];
            bf16 s[16];
            for (int e = 0; e < 8; ++e) {
                s[e]     = (bf16)((float)a0[e] + (float)b0[e]);
                s[8 + e] = (bf16)((float)a1[e] + (float)b1[e]);
            }
            bf16* dst = &Vs[vrow * 68 + vcol];
            for (int c = 0; c < 4; ++c)
                *(bf16x4*)&dst[c * 4] = *(const bf16x4*)&s[c * 4];
        }
        bf16x8 mm[4];
        {
            const bf16* mb = &maskR[(mtile0 + (size_t)jt * 256) * 32];
            for (int c = 0; c < 4; ++c) mm[c] = *(const bf16x8*)&mb[c * 8];
        }
        __syncthreads();

        f32x4 sc[2][4];
        for (int jc = 0; jc < 4; ++jc) {
            bf16x8 kf[2], qjf[2];
            for (int kc = 0; kc < 2; ++kc) {
                const int sg = ((kc * 4 + qd) ^ lx) * 8;
                kf[kc]  = *(const bf16x8*)&Ks [(jc * 16 + ln) * 64 + sg];
                qjf[kc] = *(const bf16x8*)&QJs[(jc * 16 + ln) * 64 + sg];
            }
            for (int si = 0; si < 2; ++si) {
                f32x4 a = (f32x4){0.f, 0.f, 0.f, 0.f};
                a = mfma16(qf[si][0], kf[0], a);
                a = mfma16(qf[si][1], kf[1], a);
                a = mfma16(tkf[si][0], qjf[0], a);
                a = mfma16(tkf[si][1], qjf[1], a);
                sc[si][jc] = a;
            }
        }
        for (int si = 0; si < 2; ++si) {
            const int ibl = w * 32 + si * 16 + qd * 4;
            for (int jc = 0; jc < 4; ++jc) {
                const int jl = jc * 16 + ln;
                const int e = si * 4 + jc;
                for (int r = 0; r < 4; ++r) {
                    const float mval = (float)mm[e >> 1][(e & 1) * 4 + r];
                    const float p = exp2f(fmaf(sc[si][jc][r], c1, mval * c2));
                    psum[si][r] += p;
                    Ps[ibl + r][jl] = (bf16)p;
                }
            }
        }
        for (int kc = 0; kc < 2; ++kc) {
            bf16x8 pa[2], vb[4];
            for (int si = 0; si < 2; ++si) {
                bf16x4 lo = *(const bf16x4*)&Ps[w * 32 + si * 16 + ln][kc * 32 + qd * 8];
                bf16x4 hi = *(const bf16x4*)&Ps[w * 32 + si * 16 + ln][kc * 32 + qd * 8 + 4];
                for (int e = 0; e < 4; ++e) { pa[si][e] = lo[e]; pa[si][4 + e] = hi[e]; }
            }
            for (int dc = 0; dc < 4; ++dc) {
                bf16x4 lo = *(const bf16x4*)&Vs[(dc * 16 + ln) * 68 + kc * 32 + qd * 8];
                bf16x4 hi = *(const bf16x4*)&Vs[(dc * 16 + ln) * 68 + kc * 32 + qd * 8 + 4];
                for (int e = 0; e < 4; ++e) { vb[dc][e] = lo[e]; vb[dc][4 + e] = hi[e]; }
            }
            for (int si = 0; si < 2; ++si)
                for (int dc = 0; dc < 4; ++dc)
                    O[si][dc] = mfma16(pa[si], vb[dc], O[si][dc]);
        }
    }

    for (int si = 0; si < 2; ++si) {
        for (int m = 1; m <= 8; m <<= 1) psum[si] += shflx4(psum[si], m);
        f32x4 rl;
        for (int r = 0; r < 4; ++r) rl[r] = 1.0f / psum[si][r];
        const int ibase = i0 + w * 32 + si * 16 + qd * 4;
        for (int dc = 0; dc < 4; ++dc) {
            const int d = h * 64 + dc * 16 + ln;
            f32x4 v = O[si][dc] * rl;
            for (int r = 0; r < 4; ++r)
                ctx[((size_t)b * 1024 + ibase + r) * 1024 + d] = (bf16)v[r];
        }
    }
}

// ---------------------------------------------------------------------------
// Final GEMM: out[m][n] = ctx[m][k]*WmT[n][k] + bm, fp32 out.
// 64m x 128n tile, grid (64 my, 8 nx): same-A blocks share an XCD.
// ---------------------------------------------------------------------------
__global__ __launch_bounds__(256) void out_gemm(
    const bf16* __restrict__ A, const bf16* __restrict__ W,
    const float* __restrict__ bias, float* __restrict__ out)
{
    const int m0 = blockIdx.x * 64, n0 = blockIdx.y * 128;
    __shared__ bf16 As[64 * 64];
    __shared__ bf16 Bs[128 * 64];
    const int t = threadIdx.x, lane = t & 63, w = t >> 6;
    const int ln = lane & 15, qd = lane >> 4;
    const int wn0 = w * 32;
    const int rr = lane >> 3;
    const int cbs = ((lane & 7) ^ rr) * 8;
    const int lx = ln & 7;
    f32x4 acc[4][2];
    for (int i = 0; i < 4; ++i)
        for (int j = 0; j < 2; ++j)
            acc[i][j] = (f32x4){0.f, 0.f, 0.f, 0.f};
    for (int ks = 0; ks < 16; ++ks) {
        const int bk = ks * 64;
        __syncthreads();
        for (int i = 0; i < 6; ++i) {
            const int u = w * 6 + i;
            if (u < 8) {
                glo(&A[(size_t)(m0 + u * 8 + rr) * 1024 + bk + cbs], &As[u * 512]);
            } else {
                const int sub = u - 8;
                glo(&W[(size_t)(n0 + sub * 8 + rr) * 1024 + bk + cbs], &Bs[sub * 512]);
            }
        }
        __syncthreads();
        for (int kc = 0; kc < 2; ++kc) {
            const int sg = ((kc * 4 + qd) ^ lx) * 8;
            bf16x8 af[4], bfr[2];
            for (int mi = 0; mi < 4; ++mi)
                af[mi] = *(const bf16x8*)&As[(mi * 16 + ln) * 64 + sg];
            for (int ni = 0; ni < 2; ++ni)
                bfr[ni] = *(const bf16x8*)&Bs[(wn0 + ni * 16 + ln) * 64 + sg];
            for (int mi = 0; mi < 4; ++mi)
                for (int ni = 0; ni < 2; ++ni)
                    acc[mi][ni] = mfma16(af[mi], bfr[ni], acc[mi][ni]);
        }
    }
    for (int ni = 0; ni < 2; ++ni) {
        const int n = n0 + wn0 + ni * 16 + ln;
        const float bv = bias[n];
        for (int mi = 0; mi < 4; ++mi) {
            const int mbase = m0 + mi * 16 + qd * 4;
            f32x4 v = acc[mi][ni];
            for (int r = 0; r < 4; ++r)
                out[(size_t)(mbase + r) * 1024 + n] = v[r] + bv;
        }
    }
}

// ---------------------------------------------------------------------------
extern "C" void kernel_launch(void* const* d_in, const int* in_sizes, int n_in,
                              void* d_out, int out_size, void* d_ws, size_t ws_size,
                              hipStream_t stream)
{
    (void)in_sizes; (void)n_in; (void)out_size; (void)ws_size;
    const float* query  = (const float*)d_in[0];
    const float* key    = (const float*)d_in[1];
    const float* value  = (const float*)d_in[2];
    const float* time_k = (const float*)d_in[3];
    const float* time_v = (const float*)d_in[4];
    const float* mask   = (const float*)d_in[5];
    const float* Wq  = (const float*)d_in[6];  const float* bq  = (const float*)d_in[7];
    const float* Wk  = (const float*)d_in[8];  const float* bk  = (const float*)d_in[9];
    const float* Wv  = (const float*)d_in[10]; const float* bv  = (const float*)d_in[11];
    const float* Wtk = (const float*)d_in[12]; const float* btk = (const float*)d_in[13];
    const float* Wtv = (const float*)d_in[14]; const float* btv = (const float*)d_in[15];
    const float* Wm  = (const float*)d_in[16]; const float* bm  = (const float*)d_in[17];

    bf16* ws = (bf16*)d_ws;
    const size_t MM = (size_t)1024 * 1024;
    bf16* WT    = ws;                // 6 weight slabs [N][K] bf16
    bf16* Qb    = ws + 6 * MM;       // [4096][1024]
    bf16* Kb    = ws + 10 * MM;
    bf16* TKb   = ws + 14 * MM;
    bf16* VsTa  = ws + 18 * MM;      // [b*1024 + h*64 + d][s]
    bf16* VsTb  = ws + 22 * MM;
    bf16* ctx   = ws + 26 * MM;      // [4096][1024]  (60 MB total)
    bf16* maskR = (bf16*)d_out;      // 8 MB scratch in d_out; dead before out_gemm

    PrepArgs pp;
    pp.w[0] = Wq; pp.w[1] = Wk; pp.w[2] = Wv; pp.w[3] = Wtk; pp.w[4] = Wtv; pp.w[5] = Wm;
    pp.wt = WT;
    prep_kernel<<<dim3(16, 16, 6), 256, 0, stream>>>(pp);
    maskprep_kernel<<<dim3(16, 8, 4), 256, 0, stream>>>(mask, maskR);

    ProjArgs pa;
    pa.A[0] = query;  pa.W[0] = WT + 0 * MM; pa.bias[0] = bq;  pa.out[0] = Qb;   pa.vst[0] = 0;
    pa.A[1] = key;    pa.W[1] = WT + 1 * MM; pa.bias[1] = bk;  pa.out[1] = Kb;   pa.vst[1] = 0;
    pa.A[2] = time_k; pa.W[2] = WT + 3 * MM; pa.bias[2] = btk; pa.out[2] = TKb;  pa.vst[2] = 0;
    pa.A[3] = value;  pa.W[3] = WT + 2 * MM; pa.bias[3] = bv;  pa.out[3] = VsTa; pa.vst[3] = 1;
    pa.A[4] = time_v; pa.W[4] = WT + 4 * MM; pa.bias[4] = btv; pa.out[4] = VsTb; pa.vst[4] = 1;
    proj_gemm<<<dim3(32, 8, 5), 256, 0, stream>>>(pa);

    attn6_kernel<<<dim3(16, 8, 4), 256, 0, stream>>>(
        Qb, Kb, TKb, VsTa, VsTb, maskR, ctx);
    out_gemm<<<dim3(64, 8), 256, 0, stream>>>(ctx, WT + 5 * MM, bm, (float*)d_out);
}

// Round 12
// 323.901 us; speedup vs baseline: 1.2028x; 1.2028x over previous
//
#include <hip/hip_runtime.h>
#include <hip/hip_bf16.h>
#include <cstdint>
#include <cstddef>

typedef __bf16 bf16;
typedef bf16 bf16x8 __attribute__((ext_vector_type(8)));
typedef bf16 bf16x4 __attribute__((ext_vector_type(4)));
typedef float f32x4 __attribute__((ext_vector_type(4)));
typedef unsigned int u32;

#define DEV static __device__ __forceinline__

DEV f32x4 mfma16(bf16x8 a, bf16x8 b, f32x4 c) {
    return __builtin_amdgcn_mfma_f32_16x16x32_bf16(a, b, c, 0, 0, 0);
}

DEV f32x4 shflx4(f32x4 v, int m) {
    f32x4 r;
    for (int i = 0; i < 4; ++i) r[i] = __shfl_xor(v[i], m, 64);
    return r;
}

DEV bf16x8 cvt8(const float* p) {
    float4 f0 = *(const float4*)p;
    float4 f1 = *(const float4*)(p + 4);
    bf16x8 v;
    v[0] = (bf16)f0.x; v[1] = (bf16)f0.y; v[2] = (bf16)f0.z; v[3] = (bf16)f0.w;
    v[4] = (bf16)f1.x; v[5] = (bf16)f1.y; v[6] = (bf16)f1.z; v[7] = (bf16)f1.w;
    return v;
}

// async global->LDS, 16B/lane; global addr per-lane, LDS base wave-uniform.
DEV void glo(const bf16* g, bf16* l) {
    __builtin_amdgcn_global_load_lds(
        (const __attribute__((address_space(1))) u32*)g,
        (__attribute__((address_space(3))) u32*)l,
        16, 0, 0);
}

// XOR-swizzle (bf16, 64-col rows): LDS[row][seg] = G[row][seg^(row&7)], seg =
// 8-elem/16B chunk. Fragment k-seg s of row r lives at seg s^(r&7). Spreads
// same-ln lanes across all 32 banks (16-way -> 2-way free). fp32 variant does
// NOT work (32B segs alias to 4 bank positions — measured 5.1e7 conflicts, r11).

// ---------------------------------------------------------------------------
// Prep: z<6 : weight transpose+cvt W[K][N]fp32 -> Wt[N][K]bf16
//       z 6..10 : flat fp32->bf16 cvt of the 5 activations (lane-coalesced)
// ---------------------------------------------------------------------------
struct PrepArgs {
    const float* w[6];
    const float* act[5];
    bf16* wt;
    bf16* actbf[5];
};

__global__ __launch_bounds__(256) void prep_kernel(PrepArgs p)
{
    const int z = blockIdx.z;
    const int t = threadIdx.x;
    if (z < 6) {
        __shared__ bf16 tile[64][72];
        const float* src = p.w[z];
        bf16* out = p.wt + (size_t)z * 1024 * 1024;
        const int r = t >> 3, c8 = (t & 7) * 8;
        const int row0 = blockIdx.y * 64, col0 = blockIdx.x * 64;
        *(bf16x8*)&tile[r][c8]      = cvt8(&src[(size_t)(row0 + r) * 1024 + col0 + c8]);
        *(bf16x8*)&tile[r + 32][c8] = cvt8(&src[(size_t)(row0 + r + 32) * 1024 + col0 + c8]);
        __syncthreads();
        for (int half = 0; half < 2; ++half) {
            int rr = r + half * 32;
            bf16x8 v;
            for (int j = 0; j < 8; ++j) v[j] = tile[c8 + j][rr];
            *(bf16x8*)&out[(size_t)(col0 + rr) * 1024 + row0 + c8] = v;
        }
    } else {
        const float* src = p.act[z - 6];
        bf16* dst = p.actbf[z - 6];
        const size_t chunk = (size_t)(blockIdx.y * 16 + blockIdx.x) * 16384;
        for (int c = 0; c < 8; ++c) {
            const size_t off = chunk + (size_t)c * 2048 + (size_t)t * 8;
            *(bf16x8*)&dst[off] = cvt8(&src[off]);
        }
    }
}

// ---------------------------------------------------------------------------
// maskprep: mask[b][i][j] fp32 -> maskR[(b,it,jt)][tid][e] bf16, e=(si*4+jc)*4+r
// grid (16 jt, 8 it, 4 b), 256 threads.
// ---------------------------------------------------------------------------
__global__ __launch_bounds__(256) void maskprep_kernel(
    const float* __restrict__ mask, bf16* __restrict__ maskR)
{
    const int jt = blockIdx.x, it = blockIdx.y, b = blockIdx.z;
    __shared__ bf16 Mt[128 * 72];
    const int t = threadIdx.x, lane = t & 63, w = t >> 6;
    const int ln = lane & 15, qd = lane >> 4;
    {
        const int il = t >> 1, jh = (t & 1) * 32;
        const float* src = &mask[((size_t)b * 1024 + it * 128 + il) * 1024 + jt * 64 + jh];
        *(bf16x8*)&Mt[il * 72 + jh]      = cvt8(src);
        *(bf16x8*)&Mt[il * 72 + jh + 8]  = cvt8(src + 8);
        *(bf16x8*)&Mt[il * 72 + jh + 16] = cvt8(src + 16);
        *(bf16x8*)&Mt[il * 72 + jh + 24] = cvt8(src + 24);
    }
    __syncthreads();
    bf16 m[32];
    for (int si = 0; si < 2; ++si)
        for (int jc = 0; jc < 4; ++jc)
            for (int r = 0; r < 4; ++r) {
                const int il = w * 32 + si * 16 + qd * 4 + r;
                const int jl = jc * 16 + ln;
                m[(si * 4 + jc) * 4 + r] = Mt[il * 72 + jl];
            }
    bf16* dst = &maskR[((((size_t)b * 8 + it) * 16 + jt) * 256 + t) * 32];
    for (int c = 0; c < 4; ++c)
        *(bf16x8*)&dst[c * 8] = *(const bf16x8*)&m[c * 8];
}

// ---------------------------------------------------------------------------
// Projection GEMMs, 5 z-slices, all-bf16 (round-9 verified: 0 conflicts),
// both operands glo+swizzle. Grid (32 my, 8 nx, 5): same-A blocks share an
// XCD (linear%8 = my%8) -> A fetched once per XCD (r11: FETCH 169->82 MB).
// 128x128 tile, 4 waves x 64x64, BK=64.
// ---------------------------------------------------------------------------
struct ProjArgs {
    const bf16* A[5];
    const bf16* W[5];
    const float* bias[5];
    bf16* out[5];
    int vst[5];
};

__global__ __launch_bounds__(256) void proj_gemm(ProjArgs pa)
{
    const int z = blockIdx.z;
    const bf16* A = pa.A[z];
    const bf16* W = pa.W[z];
    const int m0 = blockIdx.x * 128, n0 = blockIdx.y * 128;
    __shared__ bf16 As[128 * 64];
    __shared__ bf16 Bs[128 * 64];
    const int t = threadIdx.x, lane = t & 63, w = t >> 6;
    const int ln = lane & 15, qd = lane >> 4;
    const int wm0 = (w >> 1) * 64, wn0 = (w & 1) * 64;
    const int sub0 = w * 4;
    const int rr = lane >> 3;
    const int cbs = (((lane & 7) ^ rr)) * 8;   // swizzled source column
    const int lx = ln & 7;                     // row&7 for fragment rows
    f32x4 acc[4][4];
    for (int i = 0; i < 4; ++i)
        for (int j = 0; j < 4; ++j)
            acc[i][j] = (f32x4){0.f, 0.f, 0.f, 0.f};
    for (int ks = 0; ks < 16; ++ks) {
        const int bk = ks * 64;
        __syncthreads();
        for (int i = 0; i < 4; ++i) {
            const int row = (sub0 + i) * 8 + rr;
            glo(&W[(size_t)(n0 + row) * 1024 + bk + cbs], &Bs[(sub0 + i) * 512]);
            glo(&A[(size_t)(m0 + row) * 1024 + bk + cbs], &As[(sub0 + i) * 512]);
        }
        __syncthreads();
        for (int kc = 0; kc < 2; ++kc) {
            const int sg = ((kc * 4 + qd) ^ lx) * 8;
            bf16x8 af[4], bfr[4];
            for (int mi = 0; mi < 4; ++mi)
                af[mi] = *(const bf16x8*)&As[(wm0 + mi * 16 + ln) * 64 + sg];
            for (int ni = 0; ni < 4; ++ni)
                bfr[ni] = *(const bf16x8*)&Bs[(wn0 + ni * 16 + ln) * 64 + sg];
            for (int mi = 0; mi < 4; ++mi)
                for (int ni = 0; ni < 4; ++ni)
                    acc[mi][ni] = mfma16(af[mi], bfr[ni], acc[mi][ni]);
        }
    }
    const float* bias = pa.bias[z];
    bf16* out = pa.out[z];
    const int vst = pa.vst[z];
    for (int ni = 0; ni < 4; ++ni) {
        const int n = n0 + wn0 + ni * 16 + ln;
        const float bv = bias[n];
        for (int mi = 0; mi < 4; ++mi) {
            const int mbase = m0 + wm0 + mi * 16 + qd * 4;
            f32x4 v = acc[mi][ni];
            if (vst) {
                const int b = mbase >> 10, s = mbase & 1023;
                bf16x4 pk;
                for (int r = 0; r < 4; ++r) pk[r] = (bf16)(v[r] + bv);
                *(bf16x4*)&out[((size_t)(b * 1024 + n)) * 1024 + s] = pk;
            } else {
                for (int r = 0; r < 4; ++r)
                    out[(size_t)(mbase + r) * 1024 + n] = (bf16)(v[r] + bv);
            }
        }
    }
}

// ---------------------------------------------------------------------------
// Attention (attn6, round-9 verified): i-tile 128, j-tile 64,
// grid (16h,8it,4b)=512; K/QJ glo+swizzle; V=Va+Vb into pad-68 Vs; mask from
// maskR registers; Ps pad-68, b64 PV reads.
// ---------------------------------------------------------------------------
__global__ __launch_bounds__(256) void attn6_kernel(
    const bf16* __restrict__ Qb, const bf16* __restrict__ Kb, const bf16* __restrict__ TKb,
    const bf16* __restrict__ Va, const bf16* __restrict__ Vb,
    const bf16* __restrict__ maskR, bf16* __restrict__ ctx)
{
    const int h = blockIdx.x, it = blockIdx.y, b = blockIdx.z;
    const int i0 = it * 128;
    __shared__ bf16 Ks[64 * 64];
    __shared__ bf16 QJs[64 * 64];
    __shared__ bf16 Vs[64 * 68];
    __shared__ bf16 Ps[128][68];
    const int t = threadIdx.x, lane = t & 63, w = t >> 6;
    const int ln = lane & 15, qd = lane >> 4;
    const int lx = ln & 7;
    const size_t baseQ = ((size_t)b * 1024) * 1024 + (size_t)h * 64;

    bf16x8 qf[2][2], tkf[2][2];
    for (int si = 0; si < 2; ++si) {
        const size_t row = (size_t)(i0 + w * 32 + si * 16 + ln);
        for (int kc = 0; kc < 2; ++kc) {
            qf[si][kc]  = *(const bf16x8*)&Qb [baseQ + row * 1024 + kc * 32 + qd * 8];
            tkf[si][kc] = *(const bf16x8*)&TKb[baseQ + row * 1024 + kc * 32 + qd * 8];
        }
    }

    f32x4 O[2][4];
    f32x4 psum[2];
    for (int si = 0; si < 2; ++si) {
        psum[si] = (f32x4){0.f, 0.f, 0.f, 0.f};
        for (int dc = 0; dc < 4; ++dc) O[si][dc] = (f32x4){0.f, 0.f, 0.f, 0.f};
    }

    const float c1 = 0.045084439f;   // log2(e)/32
    const float c2 = 1.442695041f;   // log2(e)

    const size_t mtile0 = (((size_t)b * 8 + it) * 16) * 256 + t;

    for (int jt = 0; jt < 16; ++jt) {
        const int j0 = jt * 64;
        __syncthreads();
        {
            const int rr = lane >> 3;
            const int cbs = ((lane & 7) ^ rr) * 8;
            for (int i = 0; i < 4; ++i) {
                const int u = w * 4 + i;
                if (u < 8) {
                    glo(&Kb[baseQ + (size_t)(j0 + u * 8 + rr) * 1024 + cbs], &Ks[u * 512]);
                } else {
                    const int s = u - 8;
                    glo(&Qb[baseQ + (size_t)(j0 + s * 8 + rr) * 1024 + cbs], &QJs[s * 512]);
                }
            }
        }
        {
            const int vrow = t >> 2, vcol = (t & 3) * 16;
            const size_t va = ((size_t)b * 1024 + h * 64 + vrow) * 1024 + j0 + vcol;
            bf16x8 a0 = *(const bf16x8*)&Va[va];
            bf16x8 a1 = *(const bf16x8*)&Va[va + 8];
            bf16x8 b0 = *(const bf16x8*)&Vb[va];
            bf16x8 b1 = *(const bf16x8*)&Vb[va + 8];
            bf16 s[16];
            for (int e = 0; e < 8; ++e) {
                s[e]     = (bf16)((float)a0[e] + (float)b0[e]);
                s[8 + e] = (bf16)((float)a1[e] + (float)b1[e]);
            }
            bf16* dst = &Vs[vrow * 68 + vcol];
            for (int c = 0; c < 4; ++c)
                *(bf16x4*)&dst[c * 4] = *(const bf16x4*)&s[c * 4];
        }
        bf16x8 mm[4];
        {
            const bf16* mb = &maskR[(mtile0 + (size_t)jt * 256) * 32];
            for (int c = 0; c < 4; ++c) mm[c] = *(const bf16x8*)&mb[c * 8];
        }
        __syncthreads();

        f32x4 sc[2][4];
        for (int jc = 0; jc < 4; ++jc) {
            bf16x8 kf[2], qjf[2];
            for (int kc = 0; kc < 2; ++kc) {
                const int sg = ((kc * 4 + qd) ^ lx) * 8;
                kf[kc]  = *(const bf16x8*)&Ks [(jc * 16 + ln) * 64 + sg];
                qjf[kc] = *(const bf16x8*)&QJs[(jc * 16 + ln) * 64 + sg];
            }
            for (int si = 0; si < 2; ++si) {
                f32x4 a = (f32x4){0.f, 0.f, 0.f, 0.f};
                a = mfma16(qf[si][0], kf[0], a);
                a = mfma16(qf[si][1], kf[1], a);
                a = mfma16(tkf[si][0], qjf[0], a);
                a = mfma16(tkf[si][1], qjf[1], a);
                sc[si][jc] = a;
            }
        }
        for (int si = 0; si < 2; ++si) {
            const int ibl = w * 32 + si * 16 + qd * 4;
            for (int jc = 0; jc < 4; ++jc) {
                const int jl = jc * 16 + ln;
                const int e = si * 4 + jc;
                for (int r = 0; r < 4; ++r) {
                    const float mval = (float)mm[e >> 1][(e & 1) * 4 + r];
                    const float p = exp2f(fmaf(sc[si][jc][r], c1, mval * c2));
                    psum[si][r] += p;
                    Ps[ibl + r][jl] = (bf16)p;
                }
            }
        }
        for (int kc = 0; kc < 2; ++kc) {
            bf16x8 pa[2], vb[4];
            for (int si = 0; si < 2; ++si) {
                bf16x4 lo = *(const bf16x4*)&Ps[w * 32 + si * 16 + ln][kc * 32 + qd * 8];
                bf16x4 hi = *(const bf16x4*)&Ps[w * 32 + si * 16 + ln][kc * 32 + qd * 8 + 4];
                for (int e = 0; e < 4; ++e) { pa[si][e] = lo[e]; pa[si][4 + e] = hi[e]; }
            }
            for (int dc = 0; dc < 4; ++dc) {
                bf16x4 lo = *(const bf16x4*)&Vs[(dc * 16 + ln) * 68 + kc * 32 + qd * 8];
                bf16x4 hi = *(const bf16x4*)&Vs[(dc * 16 + ln) * 68 + kc * 32 + qd * 8 + 4];
                for (int e = 0; e < 4; ++e) { vb[dc][e] = lo[e]; vb[dc][4 + e] = hi[e]; }
            }
            for (int si = 0; si < 2; ++si)
                for (int dc = 0; dc < 4; ++dc)
                    O[si][dc] = mfma16(pa[si], vb[dc], O[si][dc]);
        }
    }

    for (int si = 0; si < 2; ++si) {
        for (int m = 1; m <= 8; m <<= 1) psum[si] += shflx4(psum[si], m);
        f32x4 rl;
        for (int r = 0; r < 4; ++r) rl[r] = 1.0f / psum[si][r];
        const int ibase = i0 + w * 32 + si * 16 + qd * 4;
        for (int dc = 0; dc < 4; ++dc) {
            const int d = h * 64 + dc * 16 + ln;
            f32x4 v = O[si][dc] * rl;
            for (int r = 0; r < 4; ++r)
                ctx[((size_t)b * 1024 + ibase + r) * 1024 + d] = (bf16)v[r];
        }
    }
}

// ---------------------------------------------------------------------------
// Final GEMM: out[m][n] = ctx[m][k]*WmT[n][k] + bm, fp32 out.
// 64m x 128n tile, grid (64 my, 8 nx): same-A blocks share an XCD.
// ---------------------------------------------------------------------------
__global__ __launch_bounds__(256) void out_gemm(
    const bf16* __restrict__ A, const bf16* __restrict__ W,
    const float* __restrict__ bias, float* __restrict__ out)
{
    const int m0 = blockIdx.x * 64, n0 = blockIdx.y * 128;
    __shared__ bf16 As[64 * 64];
    __shared__ bf16 Bs[128 * 64];
    const int t = threadIdx.x, lane = t & 63, w = t >> 6;
    const int ln = lane & 15, qd = lane >> 4;
    const int wn0 = w * 32;
    const int rr = lane >> 3;
    const int cbs = ((lane & 7) ^ rr) * 8;
    const int lx = ln & 7;
    f32x4 acc[4][2];
    for (int i = 0; i < 4; ++i)
        for (int j = 0; j < 2; ++j)
            acc[i][j] = (f32x4){0.f, 0.f, 0.f, 0.f};
    for (int ks = 0; ks < 16; ++ks) {
        const int bk = ks * 64;
        __syncthreads();
        for (int i = 0; i < 6; ++i) {
            const int u = w * 6 + i;
            if (u < 8) {
                glo(&A[(size_t)(m0 + u * 8 + rr) * 1024 + bk + cbs], &As[u * 512]);
            } else {
                const int sub = u - 8;
                glo(&W[(size_t)(n0 + sub * 8 + rr) * 1024 + bk + cbs], &Bs[sub * 512]);
            }
        }
        __syncthreads();
        for (int kc = 0; kc < 2; ++kc) {
            const int sg = ((kc * 4 + qd) ^ lx) * 8;
            bf16x8 af[4], bfr[2];
            for (int mi = 0; mi < 4; ++mi)
                af[mi] = *(const bf16x8*)&As[(mi * 16 + ln) * 64 + sg];
            for (int ni = 0; ni < 2; ++ni)
                bfr[ni] = *(const bf16x8*)&Bs[(wn0 + ni * 16 + ln) * 64 + sg];
            for (int mi = 0; mi < 4; ++mi)
                for (int ni = 0; ni < 2; ++ni)
                    acc[mi][ni] = mfma16(af[mi], bfr[ni], acc[mi][ni]);
        }
    }
    for (int ni = 0; ni < 2; ++ni) {
        const int n = n0 + wn0 + ni * 16 + ln;
        const float bv = bias[n];
        for (int mi = 0; mi < 4; ++mi) {
            const int mbase = m0 + mi * 16 + qd * 4;
            f32x4 v = acc[mi][ni];
            for (int r = 0; r < 4; ++r)
                out[(size_t)(mbase + r) * 1024 + n] = v[r] + bv;
        }
    }
}

// ---------------------------------------------------------------------------
extern "C" void kernel_launch(void* const* d_in, const int* in_sizes, int n_in,
                              void* d_out, int out_size, void* d_ws, size_t ws_size,
                              hipStream_t stream)
{
    (void)in_sizes; (void)n_in; (void)out_size; (void)ws_size;
    const float* query  = (const float*)d_in[0];
    const float* key    = (const float*)d_in[1];
    const float* value  = (const float*)d_in[2];
    const float* time_k = (const float*)d_in[3];
    const float* time_v = (const float*)d_in[4];
    const float* mask   = (const float*)d_in[5];
    const float* Wq  = (const float*)d_in[6];  const float* bq  = (const float*)d_in[7];
    const float* Wk  = (const float*)d_in[8];  const float* bk  = (const float*)d_in[9];
    const float* Wv  = (const float*)d_in[10]; const float* bv  = (const float*)d_in[11];
    const float* Wtk = (const float*)d_in[12]; const float* btk = (const float*)d_in[13];
    const float* Wtv = (const float*)d_in[14]; const float* btv = (const float*)d_in[15];
    const float* Wm  = (const float*)d_in[16]; const float* bm  = (const float*)d_in[17];

    bf16* ws = (bf16*)d_ws;
    const size_t MM = (size_t)1024 * 1024;
    bf16* WT    = ws;                // 6 weight slabs [N][K] bf16
    bf16* qbf   = ws + 6 * MM;       // bf16 activations (dead after proj)
    bf16* kbf   = ws + 10 * MM;
    bf16* vbf   = ws + 14 * MM;
    bf16* tkbf  = ws + 18 * MM;
    bf16* tvbf  = ws + 22 * MM;
    bf16* Qb    = ws + 26 * MM;
    bf16* Kb    = ws + 30 * MM;
    bf16* TKb   = ws + 34 * MM;
    bf16* VsTa  = ws + 38 * MM;      // [b*1024 + h*64 + d][s]
    bf16* VsTb  = ws + 42 * MM;      // (92 MB total, proven available r9)
    bf16* ctx   = ws + 6 * MM;       // reuse qbf slab
    bf16* maskR = (bf16*)d_out;      // 8 MB scratch in d_out; dead before out_gemm

    PrepArgs pp;
    pp.w[0] = Wq; pp.w[1] = Wk; pp.w[2] = Wv; pp.w[3] = Wtk; pp.w[4] = Wtv; pp.w[5] = Wm;
    pp.wt = WT;
    pp.act[0] = query; pp.act[1] = key; pp.act[2] = value;
    pp.act[3] = time_k; pp.act[4] = time_v;
    pp.actbf[0] = qbf; pp.actbf[1] = kbf; pp.actbf[2] = vbf;
    pp.actbf[3] = tkbf; pp.actbf[4] = tvbf;
    prep_kernel<<<dim3(16, 16, 11), 256, 0, stream>>>(pp);
    maskprep_kernel<<<dim3(16, 8, 4), 256, 0, stream>>>(mask, maskR);

    ProjArgs pa;
    pa.A[0] = qbf;  pa.W[0] = WT + 0 * MM; pa.bias[0] = bq;  pa.out[0] = Qb;   pa.vst[0] = 0;
    pa.A[1] = kbf;  pa.W[1] = WT + 1 * MM; pa.bias[1] = bk;  pa.out[1] = Kb;   pa.vst[1] = 0;
    pa.A[2] = tkbf; pa.W[2] = WT + 3 * MM; pa.bias[2] = btk; pa.out[2] = TKb;  pa.vst[2] = 0;
    pa.A[3] = vbf;  pa.W[3] = WT + 2 * MM; pa.bias[3] = bv;  pa.out[3] = VsTa; pa.vst[3] = 1;
    pa.A[4] = tvbf; pa.W[4] = WT + 4 * MM; pa.bias[4] = btv; pa.out[4] = VsTb; pa.vst[4] = 1;
    proj_gemm<<<dim3(32, 8, 5), 256, 0, stream>>>(pa);

    attn6_kernel<<<dim3(16, 8, 4), 256, 0, stream>>>(
        Qb, Kb, TKb, VsTa, VsTb, maskR, ctx);
    out_gemm<<<dim3(64, 8), 256, 0, stream>>>(ctx, WT + 5 * MM, bm, (float*)d_out);
}